// Round 1
// baseline (236.723 us; speedup 1.0000x reference)
//
#include <hip/hip_runtime.h>
#include <math.h>

// Reverse cumulative max (suffix max) along last dim.
// x shape: (8, 1, 2048, 2048) fp32 -> 16384 rows of W=2048.
// One 64-lane wave per row; lane l owns 32 contiguous floats.

#define ROW_W 2048
#define LANES 64
#define EPL (ROW_W / LANES)   // 32 elements per lane

__global__ __launch_bounds__(256) void suffix_max_kernel(
    const float* __restrict__ x, float* __restrict__ out, int nrows) {
  const int gtid = blockIdx.x * blockDim.x + threadIdx.x;
  const int row  = gtid >> 6;          // wave index == row index
  const int lane = threadIdx.x & 63;
  if (row >= nrows) return;

  const float* rin  = x   + (size_t)row * ROW_W + lane * EPL;
  float*       rout = out + (size_t)row * ROW_W + lane * EPL;

  float v[EPL];
  const float4* rp = (const float4*)rin;
#pragma unroll
  for (int k = 0; k < EPL / 4; ++k) {
    float4 t = rp[k];
    v[4 * k + 0] = t.x;
    v[4 * k + 1] = t.y;
    v[4 * k + 2] = t.z;
    v[4 * k + 3] = t.w;
  }

  // In-register suffix max over this lane's 32 elements.
#pragma unroll
  for (int i = EPL - 2; i >= 0; --i) v[i] = fmaxf(v[i], v[i + 1]);

  // Wave-wide inclusive suffix-max scan of per-lane chunk maxes (v[0]).
  float inc = v[0];
#pragma unroll
  for (int off = 1; off < LANES; off <<= 1) {
    float o = __shfl_down(inc, off, LANES);
    if (lane + off < LANES) inc = fmaxf(inc, o);
  }
  // Exclusive suffix (max of all chunks strictly to the right).
  float excl = __shfl_down(inc, 1, LANES);
  if (lane == 63) excl = -INFINITY;

#pragma unroll
  for (int i = 0; i < EPL; ++i) v[i] = fmaxf(v[i], excl);

  float4* op = (float4*)rout;
#pragma unroll
  for (int k = 0; k < EPL / 4; ++k) {
    float4 t;
    t.x = v[4 * k + 0];
    t.y = v[4 * k + 1];
    t.z = v[4 * k + 2];
    t.w = v[4 * k + 3];
    op[k] = t;
  }
}

extern "C" void kernel_launch(void* const* d_in, const int* in_sizes, int n_in,
                              void* d_out, int out_size, void* d_ws, size_t ws_size,
                              hipStream_t stream) {
  const float* x = (const float*)d_in[0];
  float* out = (float*)d_out;
  const int nrows = out_size / ROW_W;          // 16384
  const int waves_per_block = 256 / 64;        // 4 rows per block
  const int blocks = (nrows + waves_per_block - 1) / waves_per_block;
  suffix_max_kernel<<<blocks, 256, 0, stream>>>(x, out, nrows);
}

// Round 2
// 229.516 us; speedup vs baseline: 1.0314x; 1.0314x over previous
//
#include <hip/hip_runtime.h>
#include <math.h>

// Reverse cumulative max (suffix max) along last dim.
// x: (8,1,2048,2048) fp32 -> 16384 rows of W=2048. One wave per row.
// Lane l owns 32 contiguous floats (one 128B line): register-direct load+scan.
// Output is transposed through XOR-swizzled LDS so every global store
// instruction is a fully-coalesced 1-KiB wave store (fixes 16B/line write
// fragmentation that capped round 1 at 2.3 TB/s).

#define ROW_W 2048
#define LANES 64
#define EPL (ROW_W / LANES)      // 32 floats per lane
#define F4_PER_LANE (EPL / 4)    // 8 float4 per lane
#define F4_PER_ROW (ROW_W / 4)   // 512 float4 per row
#define WAVES_PER_BLOCK 4

__global__ __launch_bounds__(256) void suffix_max_kernel(
    const float* __restrict__ x, float* __restrict__ out, int nrows) {
  __shared__ float4 lds[WAVES_PER_BLOCK][F4_PER_ROW];  // 32 KiB/block

  const int wave = threadIdx.x >> 6;
  const int lane = threadIdx.x & 63;
  const int row  = blockIdx.x * WAVES_PER_BLOCK + wave;
  const bool valid = (row < nrows);

  float4 v[F4_PER_LANE];
  if (valid) {
    const float4* rin =
        (const float4*)(x + (size_t)row * ROW_W) + lane * F4_PER_LANE;
#pragma unroll
    for (int k = 0; k < F4_PER_LANE; ++k) v[k] = rin[k];
  } else {
#pragma unroll
    for (int k = 0; k < F4_PER_LANE; ++k) v[k] = make_float4(0.f, 0.f, 0.f, 0.f);
  }

  // Serial suffix max within the lane's 32 elements (right-to-left).
  float run = -INFINITY;
#pragma unroll
  for (int k = F4_PER_LANE - 1; k >= 0; --k) {
    v[k].w = fmaxf(v[k].w, run);
    v[k].z = fmaxf(v[k].z, v[k].w);
    v[k].y = fmaxf(v[k].y, v[k].z);
    v[k].x = fmaxf(v[k].x, v[k].y);
    run = v[k].x;  // inclusive suffix max of this lane's chunk
  }

  // Wave-wide inclusive suffix scan of per-lane maxes.
  float inc = run;
#pragma unroll
  for (int off = 1; off < LANES; off <<= 1) {
    float o = __shfl_down(inc, off, LANES);
    if (lane + off < LANES) inc = fmaxf(inc, o);
  }
  float excl = __shfl_down(inc, 1, LANES);
  if (lane == 63) excl = -INFINITY;

  // Fold right-neighbor suffix into all 32 values.
#pragma unroll
  for (int k = 0; k < F4_PER_LANE; ++k) {
    v[k].x = fmaxf(v[k].x, excl);
    v[k].y = fmaxf(v[k].y, excl);
    v[k].z = fmaxf(v[k].z, excl);
    v[k].w = fmaxf(v[k].w, excl);
  }

  // Transpose through LDS with XOR swizzle sigma(j) = j ^ ((j>>3)&7).
  // Write side: j = 8*lane + k  -> slot = 8*lane + (k ^ (lane&7))
  if (valid) {
#pragma unroll
    for (int k = 0; k < F4_PER_LANE; ++k) {
      int slot = 8 * lane + (k ^ (lane & 7));
      lds[wave][slot] = v[k];
    }
  }
  __syncthreads();

  // Read side: j = 64*k + lane -> slot = 64*k + (lane ^ (lane>>3)).
  // Global store: lane i writes float4 #(64k+i) -> contiguous 1 KiB per instr.
  if (valid) {
    float4* rowout = (float4*)(out + (size_t)row * ROW_W);
#pragma unroll
    for (int k = 0; k < F4_PER_LANE; ++k) {
      int slot = 64 * k + (lane ^ (lane >> 3));
      rowout[64 * k + lane] = lds[wave][slot];
    }
  }
}

extern "C" void kernel_launch(void* const* d_in, const int* in_sizes, int n_in,
                              void* d_out, int out_size, void* d_ws, size_t ws_size,
                              hipStream_t stream) {
  const float* x = (const float*)d_in[0];
  float* out = (float*)d_out;
  const int nrows = out_size / ROW_W;  // 16384
  const int blocks = (nrows + WAVES_PER_BLOCK - 1) / WAVES_PER_BLOCK;
  suffix_max_kernel<<<blocks, 256, 0, stream>>>(x, out, nrows);
}